// Round 1
// baseline (122.883 us; speedup 1.0000x reference)
//
#include <hip/hip_runtime.h>

typedef unsigned short u16;
typedef __attribute__((ext_vector_type(4))) float f32x4;
typedef __attribute__((ext_vector_type(8))) short bf16x8;
typedef __attribute__((ext_vector_type(4))) u16 u16x4;

#define MFMA(a, b, c) __builtin_amdgcn_mfma_f32_16x16x32_bf16(a, b, c, 0, 0, 0)

__device__ __forceinline__ u16 f2bf(float f) {
    unsigned u = __float_as_uint(f);
    u += 0x7fffu + ((u >> 16) & 1u);   // round-to-nearest-even
    return (u16)(u >> 16);
}

__device__ __forceinline__ void load_lds16(const void* g, void* l) {
    __builtin_amdgcn_global_load_lds((const __attribute__((address_space(1))) void*)g,
                                     (__attribute__((address_space(3))) void*)l,
                                     16, 0, 0);
}

// ---------------------------------------------------------------------------
// Kernel 1: pack Wq|Wk|Wv (fp32 [1024][64] each) -> Wt bf16 [192][1024] (transposed)
// ---------------------------------------------------------------------------
__global__ void wt_pack(const float* __restrict__ Wq, const float* __restrict__ Wk,
                        const float* __restrict__ Wv, u16* __restrict__ Wt) {
    int idx = blockIdx.x * 256 + threadIdx.x;     // 192*1024 = 196608 total
    int n = idx >> 10, kk = idx & 1023;
    const float* W = (n < 64) ? Wq : (n < 128 ? Wk : Wv);
    Wt[idx] = f2bf(W[kk * 64 + (n & 63)]);
}

// ---------------------------------------------------------------------------
// Kernel 2: qkv projection. x fp32 [16384][1024] @ Wt^T -> q,k bf16 [16384][64],
// vT bf16 [8][64][2048]. Zero LDS / zero barriers: A-frags reg-converted from
// global fp32, B-frags read from L2-resident Wt.
// BM=64, 4 waves (2x2), each wave 32 rows x 96 cols. grid = 256.
// ---------------------------------------------------------------------------
__global__ __launch_bounds__(256) void qkv_gemm(const float* __restrict__ x,
                                                const u16* __restrict__ Wt,
                                                u16* __restrict__ qo,
                                                u16* __restrict__ ko,
                                                u16* __restrict__ vT) {
    const int lane = threadIdx.x & 63, wave = threadIdx.x >> 6;
    const int wr = wave >> 1, wc = wave & 1;
    const int lr = lane & 15, lg = lane >> 4;
    const int m0 = blockIdx.x * 64;

    f32x4 acc[2][6];
#pragma unroll
    for (int m = 0; m < 2; ++m)
#pragma unroll
        for (int n = 0; n < 6; ++n) acc[m][n] = (f32x4){0.f, 0.f, 0.f, 0.f};

    const float* xw = x + (size_t)(m0 + wr * 32 + lr) * 1024;
    const u16* wtb = Wt + (size_t)(wc * 96 + lr) * 1024;

    for (int k0 = 0; k0 < 1024; k0 += 64) {
#pragma unroll
        for (int kc = 0; kc < 2; ++kc) {
            const int ko_ = k0 + kc * 32 + lg * 8;
            bf16x8 a[2];
#pragma unroll
            for (int m = 0; m < 2; ++m) {
                const float* p = xw + m * 16 * 1024 + ko_;
                f32x4 f0 = *(const f32x4*)(p);
                f32x4 f1 = *(const f32x4*)(p + 4);
                bf16x8 t;
#pragma unroll
                for (int i = 0; i < 4; ++i) {
                    t[i] = (short)f2bf(f0[i]);
                    t[i + 4] = (short)f2bf(f1[i]);
                }
                a[m] = t;
            }
#pragma unroll
            for (int n = 0; n < 6; ++n) {
                bf16x8 bfr = *(const bf16x8*)(wtb + (size_t)n * 16384 + ko_);
                acc[0][n] = MFMA(a[0], bfr, acc[0][n]);
                acc[1][n] = MFMA(a[1], bfr, acc[1][n]);
            }
        }
    }

    const int bb = m0 >> 11;          // batch
    const int tb = m0 & 2047;         // t base within batch
#pragma unroll
    for (int m = 0; m < 2; ++m)
#pragma unroll
        for (int n = 0; n < 6; ++n) {
            const int col = wc * 96 + n * 16 + lr;
            const int rl = wr * 32 + m * 16 + lg * 4;
            if (col < 64) {
#pragma unroll
                for (int r = 0; r < 4; ++r)
                    qo[(size_t)(m0 + rl + r) * 64 + col] = f2bf(acc[m][n][r]);
            } else if (col < 128) {
#pragma unroll
                for (int r = 0; r < 4; ++r)
                    ko[(size_t)(m0 + rl + r) * 64 + (col - 64)] = f2bf(acc[m][n][r]);
            } else {
                u16x4 pk;
#pragma unroll
                for (int r = 0; r < 4; ++r) pk[r] = f2bf(acc[m][n][r]);
                *(u16x4*)&vT[(size_t)(bb * 64 + (col - 128)) * 2048 + tb + rl] = pk;
            }
        }
}

// ---------------------------------------------------------------------------
// Kernel 3: causal flash attention. q,k bf16 [8][2048][64], vT bf16 [8][64][2048],
// out fp32 [8][2048][64]. QB=32 (2 waves x 16 rows), KB=64. grid = 512 blocks,
// heavy q-tiles first. K/V staged via global_load_lds with XOR chunk swizzle
// (swizzle applied to the global source; LDS dest linear).
// ---------------------------------------------------------------------------
__global__ __launch_bounds__(128) void attn_fwd(const u16* __restrict__ q,
                                                const u16* __restrict__ k,
                                                const u16* __restrict__ vT,
                                                float* __restrict__ out) {
    const int bid = blockIdx.x;
    const int b = bid & 7;
    const int qt = 63 - (bid >> 3);   // heavy-first
    const int q0 = qt * 32;
    const int wave = threadIdx.x >> 6, lane = threadIdx.x & 63;
    const int lr = lane & 15, lg = lane >> 4;

    __shared__ __align__(16) u16 lK[64 * 64];      // [kv][h], chunk-swizzled
    __shared__ __align__(16) u16 lV[64 * 64];      // [h][kv], chunk-swizzled
    __shared__ __align__(16) u16 lP[2][16 * 72];   // per-wave P [16][72]

    const u16* qb = q + (size_t)b * 2048 * 64;
    const u16* kb = k + (size_t)b * 2048 * 64;
    const u16* vb = vT + (size_t)b * 64 * 2048;

    const int qrow = q0 + wave * 16 + lr;
    const bf16x8 qf0 = *(const bf16x8*)(qb + (size_t)qrow * 64 + lg * 8);
    const bf16x8 qf1 = *(const bf16x8*)(qb + (size_t)qrow * 64 + 32 + lg * 8);

    f32x4 oacc[4];
#pragma unroll
    for (int n = 0; n < 4; ++n) oacc[n] = (f32x4){0.f, 0.f, 0.f, 0.f};
    float mx[4] = {-3e38f, -3e38f, -3e38f, -3e38f};
    float ls[4] = {0.f, 0.f, 0.f, 0.f};

    const float SC = 1.4426950408889634f / 32.0f;  // log2(e)/sqrt(1024)
    const int row0 = q0 + wave * 16 + lg * 4;      // lane's first S row
    const int kv_end = q0 + 32;

    for (int kv0 = 0; kv0 < kv_end; kv0 += 64) {
        // ---- stage K, V tiles (8 x 1KB global_load_lds each, split over 2 waves)
#pragma unroll
        for (int i = 0; i < 4; ++i) {
            const int j = wave * 4 + i;
            const int row = j * 8 + (lane >> 3);
            const int c = (lane & 7) ^ (row & 7);
            load_lds16(kb + (size_t)(kv0 + row) * 64 + c * 8, &lK[j * 512]);
            load_lds16(vb + (size_t)row * 2048 + kv0 + c * 8, &lV[j * 512]);
        }
        __syncthreads();

        // ---- S = Q K^T  (16 rows x 64 cols per wave)
        f32x4 s[4];
#pragma unroll
        for (int n = 0; n < 4; ++n) {
            const int krow = n * 16 + lr;
            f32x4 a = (f32x4){0.f, 0.f, 0.f, 0.f};
            const bf16x8 kf0 = *(const bf16x8*)&lK[krow * 64 + ((lg ^ (krow & 7)) << 3)];
            a = MFMA(qf0, kf0, a);
            const bf16x8 kf1 = *(const bf16x8*)&lK[krow * 64 + (((4 + lg) ^ (krow & 7)) << 3)];
            a = MFMA(qf1, kf1, a);
            s[n] = a;
        }

        // ---- scale + causal mask + row max
        float pmax[4] = {-3e38f, -3e38f, -3e38f, -3e38f};
        const bool mask = (kv0 + 63 > q0);
#pragma unroll
        for (int n = 0; n < 4; ++n) {
            const int col = kv0 + n * 16 + lr;
#pragma unroll
            for (int r = 0; r < 4; ++r) {
                float v = s[n][r] * SC;
                if (mask && col > row0 + r) v = -3e38f;
                s[n][r] = v;
                pmax[r] = fmaxf(pmax[r], v);
            }
        }
#pragma unroll
        for (int d = 1; d < 16; d <<= 1)
#pragma unroll
            for (int r = 0; r < 4; ++r) pmax[r] = fmaxf(pmax[r], __shfl_xor(pmax[r], d));

        // ---- online softmax update
        float rowsum[4];
#pragma unroll
        for (int r = 0; r < 4; ++r) {
            const float mn = fmaxf(mx[r], pmax[r]);
            const float sc = exp2f(mx[r] - mn);
            mx[r] = mn;
            ls[r] *= sc;
#pragma unroll
            for (int n = 0; n < 4; ++n) oacc[n][r] *= sc;
            rowsum[r] = 0.f;
        }
#pragma unroll
        for (int n = 0; n < 4; ++n)
#pragma unroll
            for (int r = 0; r < 4; ++r) {
                const float p = exp2f(s[n][r] - mx[r]);
                rowsum[r] += p;
                lP[wave][(lg * 4 + r) * 72 + n * 16 + lr] = f2bf(p);
            }
#pragma unroll
        for (int d = 1; d < 16; d <<= 1)
#pragma unroll
            for (int r = 0; r < 4; ++r) rowsum[r] += __shfl_xor(rowsum[r], d);
#pragma unroll
        for (int r = 0; r < 4; ++r) ls[r] += rowsum[r];

        // ---- PV
#pragma unroll
        for (int kc = 0; kc < 2; ++kc) {
            const bf16x8 pf = *(const bf16x8*)&lP[wave][lr * 72 + kc * 32 + lg * 8];
#pragma unroll
            for (int n = 0; n < 4; ++n) {
                const int hrow = n * 16 + lr;
                const bf16x8 vf =
                    *(const bf16x8*)&lV[hrow * 64 + (((kc * 4 + lg) ^ (hrow & 7)) << 3)];
                oacc[n] = MFMA(pf, vf, oacc[n]);
            }
        }
        __syncthreads();
    }

    // ---- epilogue
    float* ob = out + ((size_t)b * 2048 + row0) * 64;
#pragma unroll
    for (int r = 0; r < 4; ++r) {
        const float inv = 1.0f / ls[r];
#pragma unroll
        for (int n = 0; n < 4; ++n) ob[r * 64 + n * 16 + lr] = oacc[n][r] * inv;
    }
}

// ---------------------------------------------------------------------------
extern "C" void kernel_launch(void* const* d_in, const int* in_sizes, int n_in,
                              void* d_out, int out_size, void* d_ws, size_t ws_size,
                              hipStream_t stream) {
    const float* x = (const float*)d_in[0];
    const float* Wq = (const float*)d_in[1];
    const float* Wk = (const float*)d_in[2];
    const float* Wv = (const float*)d_in[3];
    float* out = (float*)d_out;

    char* ws = (char*)d_ws;
    u16* Wt = (u16*)ws;                                   // 384 KB
    u16* qb = (u16*)(ws + (512 << 10));                   // 2 MB
    u16* kb = (u16*)(ws + (512 << 10) + (2 << 20));       // 2 MB
    u16* vT = (u16*)(ws + (512 << 10) + (4 << 20));       // 2 MB

    wt_pack<<<768, 256, 0, stream>>>(Wq, Wk, Wv, Wt);
    qkv_gemm<<<256, 256, 0, stream>>>(x, Wt, qb, kb, vT);
    attn_fwd<<<512, 128, 0, stream>>>(qb, kb, vT, out);
}

// Round 2
// 115.434 us; speedup vs baseline: 1.0645x; 1.0645x over previous
//
#include <hip/hip_runtime.h>

typedef unsigned short u16;
typedef __attribute__((ext_vector_type(4))) float f32x4;
typedef __attribute__((ext_vector_type(8))) short bf16x8;
typedef __attribute__((ext_vector_type(4))) u16 u16x4;

#define MFMA(a, b, c) __builtin_amdgcn_mfma_f32_16x16x32_bf16(a, b, c, 0, 0, 0)

__device__ __forceinline__ u16 f2bf(float f) {
    unsigned u = __float_as_uint(f);
    u += 0x7fffu + ((u >> 16) & 1u);   // round-to-nearest-even
    return (u16)(u >> 16);
}

// ---------------------------------------------------------------------------
// Kernel 1: pack Wq|Wk|Wv (fp32 [1024][64] each) -> Wt bf16 [192][1024] (transposed)
// ---------------------------------------------------------------------------
__global__ void wt_pack(const float* __restrict__ Wq, const float* __restrict__ Wk,
                        const float* __restrict__ Wv, u16* __restrict__ Wt) {
    int idx = blockIdx.x * 256 + threadIdx.x;     // 192*1024 = 196608 total
    int n = idx >> 10, kk = idx & 1023;
    const float* W = (n < 64) ? Wq : (n < 128 ? Wk : Wv);
    Wt[idx] = f2bf(W[kk * 64 + (n & 63)]);
}

// ---------------------------------------------------------------------------
// Kernel 2: qkv projection. x fp32 [16384][1024] @ Wt^T -> q,k bf16 [16384][64],
// vT bf16 [8][64][2048]. Zero LDS / zero barriers. BM=32, 4 waves (2 row x 2 col),
// each wave 16 rows x 96 cols. grid = 512 -> 2 blocks/CU, 2 waves/SIMD.
// ---------------------------------------------------------------------------
__global__ __launch_bounds__(256) void qkv_gemm(const float* __restrict__ x,
                                                const u16* __restrict__ Wt,
                                                u16* __restrict__ qo,
                                                u16* __restrict__ ko,
                                                u16* __restrict__ vT) {
    const int lane = threadIdx.x & 63, wave = threadIdx.x >> 6;
    const int wr = wave >> 1, wc = wave & 1;
    const int lr = lane & 15, lg = lane >> 4;
    const int m0 = blockIdx.x * 32;

    f32x4 acc[6];
#pragma unroll
    for (int n = 0; n < 6; ++n) acc[n] = (f32x4){0.f, 0.f, 0.f, 0.f};

    const float* xw = x + (size_t)(m0 + wr * 16 + lr) * 1024;
    const u16* wtb = Wt + (size_t)(wc * 96 + lr) * 1024;

    for (int k0 = 0; k0 < 1024; k0 += 64) {
#pragma unroll
        for (int kc = 0; kc < 2; ++kc) {
            const int ko_ = k0 + kc * 32 + lg * 8;
            const float* p = xw + ko_;
            f32x4 f0 = *(const f32x4*)(p);
            f32x4 f1 = *(const f32x4*)(p + 4);
            bf16x8 a;
#pragma unroll
            for (int i = 0; i < 4; ++i) {
                a[i] = (short)f2bf(f0[i]);
                a[i + 4] = (short)f2bf(f1[i]);
            }
#pragma unroll
            for (int n = 0; n < 6; ++n) {
                bf16x8 bfr = *(const bf16x8*)(wtb + (size_t)n * 16384 + ko_);
                acc[n] = MFMA(a, bfr, acc[n]);
            }
        }
    }

    const int bb = m0 >> 11;          // batch
    const int tb = m0 & 2047;         // t base within batch
#pragma unroll
    for (int n = 0; n < 6; ++n) {
        const int col = wc * 96 + n * 16 + lr;
        const int rl = wr * 16 + lg * 4;
        if (col < 64) {
#pragma unroll
            for (int r = 0; r < 4; ++r)
                qo[(size_t)(m0 + rl + r) * 64 + col] = f2bf(acc[n][r]);
        } else if (col < 128) {
#pragma unroll
            for (int r = 0; r < 4; ++r)
                ko[(size_t)(m0 + rl + r) * 64 + (col - 64)] = f2bf(acc[n][r]);
        } else {
            u16x4 pk;
#pragma unroll
            for (int r = 0; r < 4; ++r) pk[r] = f2bf(acc[n][r]);
            *(u16x4*)&vT[(size_t)(bb * 64 + (col - 128)) * 2048 + tb + rl] = pk;
        }
    }
}

// ---------------------------------------------------------------------------
// Kernel 3: split-KV causal flash attention, barrier-free.
// Each WAVE owns (batch b, 16 q-rows, 512-wide kv chunk c). K/V read directly
// from global (L2-resident; blockIdx%8==b pins batch to its XCD). LDS only for
// the wave-private P layout-transpose buffer. Partials (unnormalized O, m, l)
// to workspace; attn_combine merges.
// grid = 1024 blocks x 4 waves; wave = chunk. Heavy q-tiles first.
// ---------------------------------------------------------------------------
__global__ __launch_bounds__(256) void attn_part(const u16* __restrict__ q,
                                                 const u16* __restrict__ k,
                                                 const u16* __restrict__ vT,
                                                 float* __restrict__ Op,
                                                 float* __restrict__ Mp,
                                                 float* __restrict__ Lp) {
    const int b = blockIdx.x & 7;
    const int qt = 127 - (blockIdx.x >> 3);   // heavy-first
    const int wave = threadIdx.x >> 6, lane = threadIdx.x & 63;
    const int c = wave;                       // kv chunk id
    const int q0 = qt * 16;
    const int kv_lo = c * 512;
    const int kv_hi = min(kv_lo + 512, q0 + 16);
    if (kv_lo >= kv_hi) return;               // empty unit (wave-uniform)

    __shared__ __align__(16) u16 lP[4][16 * 72];   // per-wave P [16][72]

    const int lr = lane & 15, lg = lane >> 4;
    const u16* qb = q + (size_t)b * 2048 * 64;
    const u16* kb = k + (size_t)b * 2048 * 64;
    const u16* vb = vT + (size_t)b * 64 * 2048;

    const int qrow = q0 + lr;
    const bf16x8 qf0 = *(const bf16x8*)(qb + (size_t)qrow * 64 + lg * 8);
    const bf16x8 qf1 = *(const bf16x8*)(qb + (size_t)qrow * 64 + 32 + lg * 8);

    f32x4 oacc[4];
#pragma unroll
    for (int n = 0; n < 4; ++n) oacc[n] = (f32x4){0.f, 0.f, 0.f, 0.f};
    float mx[4] = {-3e38f, -3e38f, -3e38f, -3e38f};
    float ls[4] = {0.f, 0.f, 0.f, 0.f};

    const float SC = 1.4426950408889634f / 32.0f;  // log2(e)/sqrt(1024)
    const int row0 = q0 + lg * 4;                  // lane's first S row

    for (int kv0 = kv_lo; kv0 < kv_hi; kv0 += 64) {
        // ---- S = Q K^T  (16 rows x 64 cols), K straight from global/L2
        f32x4 s[4];
#pragma unroll
        for (int n = 0; n < 4; ++n) {
            const int krow = kv0 + n * 16 + lr;
            f32x4 a = (f32x4){0.f, 0.f, 0.f, 0.f};
            const bf16x8 kf0 = *(const bf16x8*)(kb + (size_t)krow * 64 + lg * 8);
            a = MFMA(qf0, kf0, a);
            const bf16x8 kf1 = *(const bf16x8*)(kb + (size_t)krow * 64 + 32 + lg * 8);
            a = MFMA(qf1, kf1, a);
            s[n] = a;
        }

        // ---- scale + causal mask + row max
        float pmax[4] = {-3e38f, -3e38f, -3e38f, -3e38f};
        const bool mask = (kv0 + 63 > q0);
#pragma unroll
        for (int n = 0; n < 4; ++n) {
            const int col = kv0 + n * 16 + lr;
#pragma unroll
            for (int r = 0; r < 4; ++r) {
                float v = s[n][r] * SC;
                if (mask && col > row0 + r) v = -3e38f;
                s[n][r] = v;
                pmax[r] = fmaxf(pmax[r], v);
            }
        }
#pragma unroll
        for (int d = 1; d < 16; d <<= 1)
#pragma unroll
            for (int r = 0; r < 4; ++r) pmax[r] = fmaxf(pmax[r], __shfl_xor(pmax[r], d));

        // ---- online softmax update
        float rowsum[4];
#pragma unroll
        for (int r = 0; r < 4; ++r) {
            const float mn = fmaxf(mx[r], pmax[r]);
            const float sc = exp2f(mx[r] - mn);
            mx[r] = mn;
            ls[r] *= sc;
#pragma unroll
            for (int n = 0; n < 4; ++n) oacc[n][r] *= sc;
            rowsum[r] = 0.f;
        }
#pragma unroll
        for (int n = 0; n < 4; ++n)
#pragma unroll
            for (int r = 0; r < 4; ++r) {
                const float p = exp2f(s[n][r] - mx[r]);
                rowsum[r] += p;
                lP[wave][(lg * 4 + r) * 72 + n * 16 + lr] = f2bf(p);
            }
#pragma unroll
        for (int d = 1; d < 16; d <<= 1)
#pragma unroll
            for (int r = 0; r < 4; ++r) rowsum[r] += __shfl_xor(rowsum[r], d);
#pragma unroll
        for (int r = 0; r < 4; ++r) ls[r] += rowsum[r];

        // ---- PV, V^T straight from global/L2
#pragma unroll
        for (int kc = 0; kc < 2; ++kc) {
            const bf16x8 pf = *(const bf16x8*)&lP[wave][lr * 72 + kc * 32 + lg * 8];
#pragma unroll
            for (int n = 0; n < 4; ++n) {
                const bf16x8 vf =
                    *(const bf16x8*)(vb + (size_t)(n * 16 + lr) * 2048 + kv0 + kc * 32 + lg * 8);
                oacc[n] = MFMA(pf, vf, oacc[n]);
            }
        }
    }

    // ---- write partials (unnormalized)
    const int slot = ((b << 7) + qt) * 4 + c;
    float* op = Op + (size_t)slot * 1024;
#pragma unroll
    for (int r = 0; r < 4; ++r) {
#pragma unroll
        for (int n = 0; n < 4; ++n) op[(lg * 4 + r) * 64 + n * 16 + lr] = oacc[n][r];
        if (lr == 0) {
            Mp[slot * 16 + lg * 4 + r] = mx[r];
            Lp[slot * 16 + lg * 4 + r] = ls[r];
        }
    }
}

// ---------------------------------------------------------------------------
// Kernel 4: merge <=4 kv-chunk partials per q-row, normalize, write out fp32.
// One thread per (row, col). grid = 4096 x 256.
// ---------------------------------------------------------------------------
__global__ __launch_bounds__(256) void attn_combine(const float* __restrict__ Op,
                                                    const float* __restrict__ Mp,
                                                    const float* __restrict__ Lp,
                                                    float* __restrict__ out) {
    const int gid = blockIdx.x * 256 + threadIdx.x;   // 1048576
    const int col = gid & 63;
    const int row = gid >> 6;            // b*2048 + t
    const int b = row >> 11, t = row & 2047;
    const int qt = t >> 4, i = t & 15;
    const int nc = (qt >> 5) + 1;
    const int base = ((b << 7) + qt) * 4;

    float M = -3e38f;
    for (int c = 0; c < nc; ++c) M = fmaxf(M, Mp[(base + c) * 16 + i]);
    float O = 0.f, L = 0.f;
    for (int c = 0; c < nc; ++c) {
        const float w = exp2f(Mp[(base + c) * 16 + i] - M);
        O += w * Op[(size_t)(base + c) * 1024 + i * 64 + col];
        L += w * Lp[(base + c) * 16 + i];
    }
    out[(size_t)row * 64 + col] = O / L;
}

// ---------------------------------------------------------------------------
extern "C" void kernel_launch(void* const* d_in, const int* in_sizes, int n_in,
                              void* d_out, int out_size, void* d_ws, size_t ws_size,
                              hipStream_t stream) {
    const float* x = (const float*)d_in[0];
    const float* Wq = (const float*)d_in[1];
    const float* Wk = (const float*)d_in[2];
    const float* Wv = (const float*)d_in[3];
    float* out = (float*)d_out;

    char* ws = (char*)d_ws;
    u16* Wt = (u16*)ws;                                   // 384 KB @ 0
    u16* qb = (u16*)(ws + (512 << 10));                   // 2 MB
    u16* kb = (u16*)(ws + (512 << 10) + (2 << 20));       // 2 MB
    u16* vT = (u16*)(ws + (512 << 10) + (4 << 20));       // 2 MB
    float* Op = (float*)(ws + (8 << 20));                 // 4096*1024*4 = 16.8 MB
    float* Mp = (float*)(ws + (25 << 20));                // 256 KB
    float* Lp = (float*)(ws + (25 << 20) + (512 << 10));  // 256 KB

    wt_pack<<<768, 256, 0, stream>>>(Wq, Wk, Wv, Wt);
    qkv_gemm<<<512, 256, 0, stream>>>(x, Wt, qb, kb, vT);
    attn_part<<<1024, 256, 0, stream>>>(qb, kb, vT, Op, Mp, Lp);
    attn_combine<<<4096, 256, 0, stream>>>(Op, Mp, Lp, out);
}